// Round 13
// baseline (3804.349 us; speedup 1.0000x reference)
//
#include <hip/hip_runtime.h>

typedef __attribute__((ext_vector_type(8))) short short8;
typedef __attribute__((ext_vector_type(4))) float f32x4;
typedef __attribute__((ext_vector_type(4))) unsigned short u16x4;
typedef __attribute__((ext_vector_type(4))) unsigned int u32x4;

#define S_ 512
#define B_ 64
#define E_ 256
#define H_ 256
#define NSTEP 1023  // 2*S - 1 sequential cell steps per chain

// ---------- helpers ----------
__device__ __forceinline__ unsigned short f2bf(float f) {
  unsigned u = __builtin_bit_cast(unsigned, f);
  return (unsigned short)((u + 0x7fffu + ((u >> 16) & 1u)) >> 16);  // RNE
}
__device__ __forceinline__ float bf2f(unsigned short h) {
  unsigned u = ((unsigned)h) << 16;
  return __builtin_bit_cast(float, u);
}
__device__ __forceinline__ float sigm(float x) { return 1.f / (1.f + __expf(-x)); }
__device__ __forceinline__ float tanh_(float x) {
  x = fminf(fmaxf(x, -15.f), 15.f);
  float e = __expf(-2.f * x);
  return (1.f - e) / (1.f + e);
}

// ---------- prep: x -> bf16; wx/wh packed rows p=jc*4+gate, NATURAL columns; bias combined ----------
__global__ __launch_bounds__(256) void prep9(
    const float* __restrict__ x,
    const float* __restrict__ wih_f, const float* __restrict__ whh_f,
    const float* __restrict__ bih_f, const float* __restrict__ bhh_f,
    const float* __restrict__ wih_b, const float* __restrict__ whh_b,
    const float* __restrict__ bih_b, const float* __restrict__ bhh_b,
    short* __restrict__ x_bf, short* __restrict__ wx, short* __restrict__ wh,
    float* __restrict__ bias_p)
{
  long i0 = (long)blockIdx.x * blockDim.x + threadIdx.x;
  long stride = (long)gridDim.x * blockDim.x;
  const long NX = (long)S_ * B_ * E_;
  const long NW = 2L * 1024 * 256;
  const long NB = 2L * 1024;

  for (long i = i0; i < NX; i += stride) x_bf[i] = (short)f2bf(x[i]);

  for (long i = i0; i < NW; i += stride) {
    int ch  = (int)(i >> 18);
    int rem = (int)(i & 262143);
    int p   = rem >> 8;              // packed row 0..1023
    int k   = rem & 255;
    int jc  = p >> 2, g = p & 3;
    long j  = (long)(g * 256 + jc);  // original gate row
    wx[i] = (short)f2bf((ch ? wih_b : wih_f)[j * 256 + k]);
    wh[i] = (short)f2bf((ch ? whh_b : whh_f)[j * 256 + k]);
  }

  for (long i = i0; i < NB; i += stride) {
    int ch = (int)(i >> 10);
    int p  = (int)(i & 1023);
    int jc = p >> 2, g = p & 3;
    int j  = g * 256 + jc;
    bias_p[i] = ch ? (bih_b[j] + bhh_b[j]) : (bih_f[j] + bhh_f[j]);
  }
}

// ---------- xz precompute (bias folded), bf16; layout xz[ch][t][jc 256][b 64][g 4] ----------
__global__ __launch_bounds__(512, 2) void xz_gemm9(
    const short* __restrict__ x_bf, const short* __restrict__ wx,
    const float* __restrict__ bias_p, short* __restrict__ xz)
{
  const int bid = blockIdx.x;
  const int ch = bid >> 9, t = bid & 511;
  const int tid = threadIdx.x;
  const int wave = tid >> 6, lane = tid & 63;
  const int l15 = lane & 15, l4 = lane >> 4;

  const short* W = wx + (long)ch * 1024 * 256;
  const short* X = x_bf + (long)t * B_ * E_;

  f32x4 acc[8][4];
#pragma unroll
  for (int mt = 0; mt < 8; ++mt)
#pragma unroll
    for (int nt = 0; nt < 4; ++nt) acc[mt][nt] = (f32x4){0.f, 0.f, 0.f, 0.f};

#pragma unroll
  for (int ks = 0; ks < 8; ++ks) {
    int k0 = ks * 32 + l4 * 8;
    short8 bfr[4];
#pragma unroll
    for (int nt = 0; nt < 4; ++nt)
      bfr[nt] = *(const short8*)(X + (long)(nt * 16 + l15) * E_ + k0);
#pragma unroll
    for (int mt = 0; mt < 8; ++mt) {
      int p = (wave * 8 + mt) * 16 + l15;
      short8 af = *(const short8*)(W + (long)p * 256 + k0);
#pragma unroll
      for (int nt = 0; nt < 4; ++nt)
        acc[mt][nt] = __builtin_amdgcn_mfma_f32_16x16x32_bf16(af, bfr[nt], acc[mt][nt], 0, 0, 0);
    }
  }

#pragma unroll
  for (int mt = 0; mt < 8; ++mt) {
    int jc = (wave * 8 + mt) * 4 + l4;
    f32x4 b4 = *(const f32x4*)(bias_p + ch * 1024 + jc * 4);
#pragma unroll
    for (int nt = 0; nt < 4; ++nt) {
      int b = nt * 16 + l15;
      u16x4 v;
#pragma unroll
      for (int g = 0; g < 4; ++g) v[g] = f2bf(acc[mt][nt][g] + b4[g]);
      long off = (((long)(ch * 512 + t) * 256 + jc) * 64 + b) * 4;
      *(u16x4*)(xz + off) = v;
    }
  }
}

// ---------- v13 LSTM: chain-interleaved poison ring, col-major rectangles ----------
// 16 blocks = (bs 4) x (role 4), 512 threads. Each block runs BOTH chains (ch0, ch1)
// for its (bs, role): chain A's MALL round-trip hides under chain B's compute and
// vice versa. ch0 weights register-resident (64 VGPR/wave); ch1 weights in LDS (128KB).
// Ring (col-major rectangles): ring[slot4][ch2][bs4][col256][b16] bf16.
// Gate stores: wave's 2 mt x 4 cols x 16 b = 256B CONTIGUOUS -> fully coalesced 2B
// stores, no hout, no extra barrier (fixes v12's 2.5x write amplification).
// Poison protocol per chain identical to v10 (proven): poison(t+1) -> spin vmcnt acks
// -> data(t) undrained, visibility rides consumers' spins; ring depth 4, skew <= 1.
__global__ __launch_bounds__(512) void lstm13(
    const short* __restrict__ wh, const short* __restrict__ xz,
    short* __restrict__ ring, float* __restrict__ out)
{
  const int bid  = blockIdx.x;
  const int bs   = bid >> 2;
  const int role = bid & 3;
  const int tid  = threadIdx.x;
  const int wave = tid >> 6, lane = tid & 63;
  const int l15 = lane & 15, l4 = lane >> 4;

  __shared__ short wB[256 * 256];    // 128 KB: ch1 weight rows role*256..+256, swizzled
  __shared__ short hinA[16 * 256];   // 8 KB: ch0 h_{t-1}, swizzled
  __shared__ short hinB[16 * 256];   // 8 KB: ch1 h_{t-1}, swizzled

  const short* whA = wh;                   // ch0 packed rows
  const short* whB = wh + 1024 * 256;      // ch1 packed rows

  // ---- init: stage ch1 weights into LDS (swizzled); zero hin buffers ----
  {
    char* wl = (char*)wB;
#pragma unroll
    for (int c = 0; c < 16; ++c) {
      int chunk = c * 512 + tid;     // 8192 chunks of 16B
      int row = chunk >> 5;          // 0..255
      int c16 = chunk & 31;
      short8 v = *(const short8*)(whB + (long)(role * 256 + row) * 256 + c16 * 8);
      *(short8*)(wl + row * 512 + ((c16 * 16) ^ ((row & 7) << 4))) = v;
    }
    for (int i = tid; i < 16 * 256; i += 512) { hinA[i] = 0; hinB[i] = 0; }
  }

  // ---- ch0 weights register-resident: rows role*256 + wave*32 + mt*16 + l15 ----
  short8 ahA[2][8];
#pragma unroll
  for (int mt = 0; mt < 2; ++mt)
#pragma unroll
    for (int ks = 0; ks < 8; ++ks)
      ahA[mt][ks] = *(const short8*)(whA + (long)(role * 256 + wave * 32 + mt * 16 + l15) * 256 + ks * 32 + l4 * 8);

  float cstA[2], hmA[2], cstB[2], hmB[2];
#pragma unroll
  for (int mt = 0; mt < 2; ++mt) { cstA[mt] = 0.f; hmA[mt] = -2.f; cstB[mt] = 0.f; hmB[mt] = -2.f; }

  const int swzr = (l15 & 7) << 4;
  // spin/stage task: 384 active threads, 192 remote cols x 2 halves (8 rows each)
  const int colIdx = tid >> 1, halfT = tid & 1;
  const int rcol = colIdx + ((colIdx >= role * 64) ? 64 : 0);
  const int active = tid < 384;
  // per-wave weight LDS base for chain B
  const int wBbase = (wave * 32 + l15) * 512;

  __syncthreads();

  for (int t = 0; t < NSTEP; ++t) {
    const int slotP = ((t + 1) & 3), slotR = ((t + 3) & 3), slotW = (t & 3);

#pragma unroll
    for (int cc = 0; cc < 2; ++cc) {
      int tok;
      if (cc == 0) tok = (t + 1) >> 1;
      else         tok = (t == NSTEP - 1) ? (S_ - 1) : ((t & 1) ? (t >> 1) : (t >> 1) + 1);
      short* hinX = cc ? hinB : hinA;

      // ring rectangle bases (short offsets): ((slot*2 + cc)*4 + bs)*4096
      short* rP = ring + ((slotP * 2 + cc) * 4 + bs) * 4096;
      short* rR = ring + ((slotR * 2 + cc) * 4 + bs) * 4096;
      short* rW = ring + ((slotW * 2 + cc) * 4 + bs) * 4096;

      // xz addends for this chain/step (L3; issued early, consumed at gates)
      u16x4 xq[2];
#pragma unroll
      for (int mt = 0; mt < 2; ++mt) {
        int jc = role * 64 + wave * 8 + mt * 4 + l4;
        long off = (((long)(cc * 512 + tok) * 256 + jc) * 64 + (bs * 16 + l15)) * 4;
        xq[mt] = *(const u16x4*)(xz + off);
      }

      // ---- poison own rectangle (cols role*64..+64 contiguous = 2KB) in slot t+1 ----
      if (tid < 256) {
        short* pa = rP + role * 1024 + tid * 4;
        unsigned long long pv = 0xFFFFFFFFFFFFFFFFull;
        asm volatile("global_store_dwordx2 %0, %1, off sc1" :: "v"(pa), "v"(pv) : "memory");
      }

      // ---- spin+stage remote cols from slot t-1: data IS the flag ----
      if (active) {
        const short* ga = rR + rcol * 16 + halfT * 8;
        short8 hv;
        int bad;
        do {
          asm volatile("global_load_dwordx4 %0, %1, off sc1\n\ts_waitcnt vmcnt(0)"
                       : "=v"(hv) : "v"(ga) : "memory");
          u32x4 dv = __builtin_bit_cast(u32x4, hv);
          bad = 0;
#pragma unroll
          for (int i = 0; i < 4; ++i) {
            unsigned d = dv[i];
            bad |= ((d & 0xFFFFu) == 0xFFFFu) | ((d >> 16) == 0xFFFFu);
          }
        } while (__ballot(bad));
        // transpose into hin[row][col] (8 x ds_write_b16, swizzled)
#pragma unroll
        for (int j = 0; j < 8; ++j) {
          int row = halfT * 8 + j;
          *(short*)((char*)hinX + row * 512 + ((rcol * 2) ^ (j << 4))) = hv[j];
        }
      }
      __syncthreads();

      // ---- recurrent MFMAs ----
      f32x4 acc[2];
      acc[0] = (f32x4){0.f, 0.f, 0.f, 0.f};
      acc[1] = (f32x4){0.f, 0.f, 0.f, 0.f};
      const char* hr = (const char*)hinX + l15 * 512;
      if (cc == 0) {
#pragma unroll
        for (int ks = 0; ks < 8; ++ks) {
          short8 hfr = *(const short8*)(hr + ((ks * 64 + l4 * 16) ^ swzr));
          acc[0] = __builtin_amdgcn_mfma_f32_16x16x32_bf16(ahA[0][ks], hfr, acc[0], 0, 0, 0);
          acc[1] = __builtin_amdgcn_mfma_f32_16x16x32_bf16(ahA[1][ks], hfr, acc[1], 0, 0, 0);
        }
      } else {
        const char* wl = (const char*)wB;
#pragma unroll
        for (int ks = 0; ks < 8; ++ks) {
          int koff = (ks * 64 + l4 * 16) ^ swzr;
          short8 hfr = *(const short8*)(hr + koff);
          short8 w0 = *(const short8*)(wl + wBbase + koff);
          short8 w1 = *(const short8*)(wl + wBbase + 8192 + koff);
          acc[0] = __builtin_amdgcn_mfma_f32_16x16x32_bf16(w0, hfr, acc[0], 0, 0, 0);
          acc[1] = __builtin_amdgcn_mfma_f32_16x16x32_bf16(w1, hfr, acc[1], 0, 0, 0);
        }
      }
      __syncthreads();   // all hinX reads done before own-col writes below

      // ---- gates / state; own cols -> hinX (next step), data -> ring (coalesced) ----
      float* cst = cc ? cstB : cstA;
      float* hm  = cc ? hmB  : hmA;
#pragma unroll
      for (int mt = 0; mt < 2; ++mt) {
        float zi = acc[mt][0] + bf2f(xq[mt][0]);
        float zf = acc[mt][1] + bf2f(xq[mt][1]);
        float zg = acc[mt][2] + bf2f(xq[mt][2]);
        float zo = acc[mt][3] + bf2f(xq[mt][3]);
        float cv = cst[mt];
        cv = sigm(zf) * cv + sigm(zi) * tanh_(zg);
        float hh = sigm(zo) * tanh_(cv);
        cst[mt] = cv;
        hm[mt] = fmaxf(hm[mt], hh);
        unsigned short hb = f2bf(hh);
        int col = role * 64 + wave * 8 + mt * 4 + l4;
        // LDS: own col for next step (disjoint from remote stage writes)
        *(short*)((char*)hinX + l15 * 512 + ((col * 2) ^ swzr)) = (short)hb;
        // ring: col-major -> wave's 64 stores span 128B contiguous per mt
        unsigned hv32 = (unsigned)hb;
        short* ga = rW + col * 16 + l15;
        asm volatile("global_store_short %0, %1, off sc1" :: "v"(ga), "v"(hv32) : "memory");
      }
      // no trailing barrier: next phase's barrier orders hinX reuse
    }
  }

  // ---- final: running maxes, both chains ----
#pragma unroll
  for (int mt = 0; mt < 2; ++mt) {
    int jc = role * 64 + wave * 8 + mt * 4 + l4;
    long rowb = (long)(bs * 16 + l15) * (2 * H_);
    out[rowb + jc] = hmA[mt];
    out[rowb + H_ + jc] = hmB[mt];
  }
}

extern "C" void kernel_launch(void* const* d_in, const int* in_sizes, int n_in,
                              void* d_out, int out_size, void* d_ws, size_t ws_size,
                              hipStream_t stream) {
  const float* x     = (const float*)d_in[0];
  const float* wih_f = (const float*)d_in[1];
  const float* whh_f = (const float*)d_in[2];
  const float* bih_f = (const float*)d_in[3];
  const float* bhh_f = (const float*)d_in[4];
  const float* wih_b = (const float*)d_in[5];
  const float* whh_b = (const float*)d_in[6];
  const float* bih_b = (const float*)d_in[7];
  const float* bhh_b = (const float*)d_in[8];

  char* ws = (char*)d_ws;
  short* x_bf   = (short*)(ws);                 // 16,777,216 B (dead after xz_gemm9)
  short* ring   = (short*)(ws);                 // 262,144 B ring (reuses x_bf region)
  short* wx     = (short*)(ws + 16777216);      //  1,048,576 B
  short* wh     = (short*)(ws + 17825792);      //  1,048,576 B
  float* bias_p = (float*)(ws + 18874368);      //      8,192 B
  short* xz     = (short*)(ws + 18882560);      // 134,217,728 B (bf16)

  const size_t NEED = 18882560UL + 134217728UL;   // 153,100,288
  if (ws_size < NEED) return;

  prep9<<<2048, 256, 0, stream>>>(x, wih_f, whh_f, bih_f, bhh_f,
                                  wih_b, whh_b, bih_b, bhh_b,
                                  x_bf, wx, wh, bias_p);
  xz_gemm9<<<1024, 512, 0, stream>>>(x_bf, wx, bias_p, xz);

  // x_bf dead; init ring: slots 0..2 = poison (0xFF), slot 3 = zeros (h_{-1} = 0).
  hipMemsetAsync(ws, 0xFF, 196608, stream);
  hipMemsetAsync(ws + 196608, 0, 65536, stream);

  lstm13<<<16, 512, 0, stream>>>(wh, xz, ring, (float*)d_out);
}

// Round 14
// 2247.304 us; speedup vs baseline: 1.6929x; 1.6929x over previous
//
#include <hip/hip_runtime.h>

typedef __attribute__((ext_vector_type(8))) short short8;
typedef __attribute__((ext_vector_type(4))) float f32x4;
typedef __attribute__((ext_vector_type(4))) unsigned short u16x4;
typedef __attribute__((ext_vector_type(4))) unsigned int u32x4;

#define S_ 512
#define B_ 64
#define E_ 256
#define H_ 256
#define NSTEP 1023  // 2*S - 1 sequential cell steps per chain

// ---------- helpers ----------
__device__ __forceinline__ unsigned short f2bf(float f) {
  unsigned u = __builtin_bit_cast(unsigned, f);
  return (unsigned short)((u + 0x7fffu + ((u >> 16) & 1u)) >> 16);  // RNE
}
__device__ __forceinline__ float bf2f(unsigned short h) {
  unsigned u = ((unsigned)h) << 16;
  return __builtin_bit_cast(float, u);
}
__device__ __forceinline__ float sigm(float x) { return 1.f / (1.f + __expf(-x)); }
__device__ __forceinline__ float tanh_(float x) {
  x = fminf(fmaxf(x, -15.f), 15.f);
  float e = __expf(-2.f * x);
  return (1.f - e) / (1.f + e);
}

// ---------- prep: x -> bf16; wx/wh packed rows p=jc*4+gate, NATURAL columns; bias combined ----------
__global__ __launch_bounds__(256) void prep9(
    const float* __restrict__ x,
    const float* __restrict__ wih_f, const float* __restrict__ whh_f,
    const float* __restrict__ bih_f, const float* __restrict__ bhh_f,
    const float* __restrict__ wih_b, const float* __restrict__ whh_b,
    const float* __restrict__ bih_b, const float* __restrict__ bhh_b,
    short* __restrict__ x_bf, short* __restrict__ wx, short* __restrict__ wh,
    float* __restrict__ bias_p)
{
  long i0 = (long)blockIdx.x * blockDim.x + threadIdx.x;
  long stride = (long)gridDim.x * blockDim.x;
  const long NX = (long)S_ * B_ * E_;
  const long NW = 2L * 1024 * 256;
  const long NB = 2L * 1024;

  for (long i = i0; i < NX; i += stride) x_bf[i] = (short)f2bf(x[i]);

  for (long i = i0; i < NW; i += stride) {
    int ch  = (int)(i >> 18);
    int rem = (int)(i & 262143);
    int p   = rem >> 8;              // packed row 0..1023
    int k   = rem & 255;
    int jc  = p >> 2, g = p & 3;
    long j  = (long)(g * 256 + jc);  // original gate row
    wx[i] = (short)f2bf((ch ? wih_b : wih_f)[j * 256 + k]);
    wh[i] = (short)f2bf((ch ? whh_b : whh_f)[j * 256 + k]);
  }

  for (long i = i0; i < NB; i += stride) {
    int ch = (int)(i >> 10);
    int p  = (int)(i & 1023);
    int jc = p >> 2, g = p & 3;
    int j  = g * 256 + jc;
    bias_p[i] = ch ? (bih_b[j] + bhh_b[j]) : (bih_f[j] + bhh_f[j]);
  }
}

// ---------- xz precompute (bias folded), bf16; layout xz[ch][t][jc 256][b 64][g 4] ----------
__global__ __launch_bounds__(512, 2) void xz_gemm9(
    const short* __restrict__ x_bf, const short* __restrict__ wx,
    const float* __restrict__ bias_p, short* __restrict__ xz)
{
  const int bid = blockIdx.x;
  const int ch = bid >> 9, t = bid & 511;
  const int tid = threadIdx.x;
  const int wave = tid >> 6, lane = tid & 63;
  const int l15 = lane & 15, l4 = lane >> 4;

  const short* W = wx + (long)ch * 1024 * 256;
  const short* X = x_bf + (long)t * B_ * E_;

  f32x4 acc[8][4];
#pragma unroll
  for (int mt = 0; mt < 8; ++mt)
#pragma unroll
    for (int nt = 0; nt < 4; ++nt) acc[mt][nt] = (f32x4){0.f, 0.f, 0.f, 0.f};

#pragma unroll
  for (int ks = 0; ks < 8; ++ks) {
    int k0 = ks * 32 + l4 * 8;
    short8 bfr[4];
#pragma unroll
    for (int nt = 0; nt < 4; ++nt)
      bfr[nt] = *(const short8*)(X + (long)(nt * 16 + l15) * E_ + k0);
#pragma unroll
    for (int mt = 0; mt < 8; ++mt) {
      int p = (wave * 8 + mt) * 16 + l15;
      short8 af = *(const short8*)(W + (long)p * 256 + k0);
#pragma unroll
      for (int nt = 0; nt < 4; ++nt)
        acc[mt][nt] = __builtin_amdgcn_mfma_f32_16x16x32_bf16(af, bfr[nt], acc[mt][nt], 0, 0, 0);
    }
  }

#pragma unroll
  for (int mt = 0; mt < 8; ++mt) {
    int jc = (wave * 8 + mt) * 4 + l4;
    f32x4 b4 = *(const f32x4*)(bias_p + ch * 1024 + jc * 4);
#pragma unroll
    for (int nt = 0; nt < 4; ++nt) {
      int b = nt * 16 + l15;
      u16x4 v;
#pragma unroll
      for (int g = 0; g < 4; ++g) v[g] = f2bf(acc[mt][nt][g] + b4[g]);
      long off = (((long)(ch * 512 + t) * 256 + jc) * 64 + b) * 4;
      *(u16x4*)(xz + off) = v;
    }
  }
}

// ---------- v14 LSTM: v10 poison-ring (proven), 1 barrier/step + early stores ----------
// 32 blocks = (ch 2) x (bs 4) x (role 4), 512 threads. Deltas vs v10 (all intra-block):
//  * hin double-buffered -> single barrier per step
//  * own-col shortcut: gates write own 64 cols into next hin (LDS); spin covers only
//    192 remote cols (384 threads)
//  * wave-private hout (2KB): gates write 2B, same wave re-reads 16B/lane (lgkmcnt
//    only, no barrier) and issues coalesced 16B ring stores EARLY (per-wave, not
//    block-barrier-delayed). Poison->spin-vmcnt->data induction identical to v10.
__global__ __launch_bounds__(512) void lstm14(
    const short* __restrict__ wh, const short* __restrict__ xz,
    short* __restrict__ hring, float* __restrict__ out)
{
  const int bid  = blockIdx.x;
  const int ch   = bid >> 4;
  const int bs   = (bid >> 2) & 3;
  const int role = bid & 3;
  const int tid  = threadIdx.x;
  const int wave = tid >> 6, lane = tid & 63;
  const int l15 = lane & 15, l4 = lane >> 4;

  __shared__ short hin[2][16 * 256];   // 16 KB: double-buffered h_{t-1}, XOR-swizzled
  __shared__ short hout[8][16 * 8];    // 2 KB: wave-private transpose rectangles

  for (int i = tid; i < 2 * 16 * 256; i += 512) ((short*)hin)[i] = 0;

  const short* whc = wh + (long)ch * 1024 * 256;

  // register-resident weight tiles: rows role*256 + wave*32 + mt*16 + l15
  short8 ah[2][8];
#pragma unroll
  for (int mt = 0; mt < 2; ++mt)
#pragma unroll
    for (int ks = 0; ks < 8; ++ks)
      ah[mt][ks] = *(const short8*)(whc + (long)(role * 256 + wave * 32 + mt * 16 + l15) * 256 + ks * 32 + l4 * 8);

  float cst[2], hmax[2];
#pragma unroll
  for (int mt = 0; mt < 2; ++mt) { cst[mt] = 0.f; hmax[mt] = -2.f; }

  short* rb = hring + ch * 16384;        // ch base (shorts); slot stride 32768 shorts
  const int swzr = (l15 & 7) << 4;

  // poison coords (tid<256): own 64 cols, 16 rows x 16 chunks of 8B
  const int sb = tid >> 4, sc = tid & 15;
  // spin/stage coords (tid<384): 192 remote cols as 24 chunks of 8 cols x 16 rows
  const int pb = tid >> 5 >= 12 ? 0 : 0;  // (unused placeholder to keep naming clear)
  const int srow = tid / 24;              // 0..15 for tid<384
  const int schk = tid % 24;              // 0..23 remote 8-col chunk
  const int scol = (schk >= role * 8) ? (schk + 8) : schk;  // skip own 8 chunks
  const int active = tid < 384;

  __syncthreads();  // hin zero-init visible

  for (int t = 0; t < NSTEP; ++t) {
    int tok;
    if (ch == 0) tok = (t + 1) >> 1;
    else         tok = (t == NSTEP - 1) ? (S_ - 1) : ((t & 1) ? (t >> 1) : (t >> 1) + 1);

    // xz addends (cached loads; issued early, consumed at gates)
    u16x4 xq[2];
#pragma unroll
    for (int mt = 0; mt < 2; ++mt) {
      int jc = role * 64 + wave * 8 + mt * 4 + l4;
      long off = (((long)(ch * 512 + tok) * 256 + jc) * 64 + (bs * 16 + l15)) * 4;
      xq[mt] = *(const u16x4*)(xz + off);
    }

    // ---- poison own rectangle in slot (t+1)&3 (drained by this wave's spin vmcnt) ----
    if (tid < 256) {
      short* pa = rb + ((t + 1) & 3) * 32768 + (bs * 16 + sb) * 256 + role * 64 + sc * 4;
      unsigned long long pv = 0xFFFFFFFFFFFFFFFFull;
      asm volatile("global_store_dwordx2 %0, %1, off sc1" :: "v"(pa), "v"(pv) : "memory");
    }

    // ---- spin+stage 192 remote cols of h_{t-1} from slot (t+3)&3: data IS the flag ----
    if (active) {
      const short* ga = rb + ((t + 3) & 3) * 32768 + (bs * 16 + srow) * 256 + scol * 8;
      short8 hv;
      int bad;
      do {
        asm volatile("global_load_dwordx4 %0, %1, off sc1\n\ts_waitcnt vmcnt(0)"
                     : "=v"(hv) : "v"(ga) : "memory");
        u32x4 dv = __builtin_bit_cast(u32x4, hv);
        bad = 0;
#pragma unroll
        for (int i = 0; i < 4; ++i) {
          unsigned d = dv[i];
          bad |= ((d & 0xFFFFu) == 0xFFFFu) | ((d >> 16) == 0xFFFFu);
        }
      } while (__ballot(bad));
      *(short8*)((char*)hin[t & 1] + srow * 512 + ((scol * 16) ^ ((srow & 7) << 4))) = hv;
    } else {
      // drain poison for waves with no spin threads is unnecessary: waves 4-5 hold
      // tid 256..383 (active) and waves 6-7 issued no poison (tid>=384 => tid>=256).
    }
    __syncthreads();   // the ONLY barrier per step

    // ---- recurrent MFMAs: 2 M-tiles x 8 k-steps ----
    f32x4 acc[2];
    acc[0] = (f32x4){0.f, 0.f, 0.f, 0.f};
    acc[1] = (f32x4){0.f, 0.f, 0.f, 0.f};
    const char* hr = (const char*)hin[t & 1] + l15 * 512;
#pragma unroll
    for (int ks = 0; ks < 8; ++ks) {
      short8 hfr = *(const short8*)(hr + ((ks * 64 + l4 * 16) ^ swzr));
      acc[0] = __builtin_amdgcn_mfma_f32_16x16x32_bf16(ah[0][ks], hfr, acc[0], 0, 0, 0);
      acc[1] = __builtin_amdgcn_mfma_f32_16x16x32_bf16(ah[1][ks], hfr, acc[1], 0, 0, 0);
    }

    // ---- gates / state; own cols -> next hin (LDS); hout transpose (wave-private) ----
    char* hnext = (char*)hin[(t + 1) & 1] + l15 * 512;
#pragma unroll
    for (int mt = 0; mt < 2; ++mt) {
      float zi = acc[mt][0] + bf2f(xq[mt][0]);
      float zf = acc[mt][1] + bf2f(xq[mt][1]);
      float zg = acc[mt][2] + bf2f(xq[mt][2]);
      float zo = acc[mt][3] + bf2f(xq[mt][3]);
      float cc = cst[mt];
      cc = sigm(zf) * cc + sigm(zi) * tanh_(zg);
      float hh = sigm(zo) * tanh_(cc);
      cst[mt] = cc;
      hmax[mt] = fmaxf(hmax[mt], hh);
      unsigned short hb = f2bf(hh);
      int col = role * 64 + wave * 8 + mt * 4 + l4;
      *(short*)(hnext + ((col * 2) ^ swzr)) = (short)hb;       // own col for next step
      hout[wave][l15 * 8 + mt * 4 + l4] = (short)hb;           // wave-private transpose
    }
    // same-wave LDS read-back (compiler emits lgkmcnt); coalesced 16B ring stores,
    // issued per-wave EARLY (no block barrier before the store)
    if (l4 == 0) {  // 16 lanes per wave
      short8 row = *(const short8*)(&hout[wave][l15 * 8]);
      short* ga = rb + (t & 3) * 32768 + (bs * 16 + l15) * 256 + role * 64 + wave * 8;
      asm volatile("global_store_dwordx4 %0, %1, off sc1" :: "v"(ga), "v"(row) : "memory");
    }
    // no trailing barrier: hin buffers alternate; hout is wave-private; ring-store
    // visibility rides consumers' spins (v10 induction unchanged)
  }

  // ---- final: running maxes ----
#pragma unroll
  for (int mt = 0; mt < 2; ++mt) {
    int jc = role * 64 + wave * 8 + mt * 4 + l4;
    out[(long)(bs * 16 + l15) * (2 * H_) + ch * H_ + jc] = hmax[mt];
  }
}

extern "C" void kernel_launch(void* const* d_in, const int* in_sizes, int n_in,
                              void* d_out, int out_size, void* d_ws, size_t ws_size,
                              hipStream_t stream) {
  const float* x     = (const float*)d_in[0];
  const float* wih_f = (const float*)d_in[1];
  const float* whh_f = (const float*)d_in[2];
  const float* bih_f = (const float*)d_in[3];
  const float* bhh_f = (const float*)d_in[4];
  const float* wih_b = (const float*)d_in[5];
  const float* whh_b = (const float*)d_in[6];
  const float* bih_b = (const float*)d_in[7];
  const float* bhh_b = (const float*)d_in[8];

  char* ws = (char*)d_ws;
  short* x_bf   = (short*)(ws);                 // 16,777,216 B (dead after xz_gemm9)
  short* hring  = (short*)(ws);                 // 262,144 B ring (reuses x_bf region)
  short* wx     = (short*)(ws + 16777216);      //  1,048,576 B
  short* wh     = (short*)(ws + 17825792);      //  1,048,576 B
  float* bias_p = (float*)(ws + 18874368);      //      8,192 B
  short* xz     = (short*)(ws + 18882560);      // 134,217,728 B (bf16)

  const size_t NEED = 18882560UL + 134217728UL;   // 153,100,288
  if (ws_size < NEED) return;

  prep9<<<2048, 256, 0, stream>>>(x, wih_f, whh_f, bih_f, bhh_f,
                                  wih_b, whh_b, bih_b, bhh_b,
                                  x_bf, wx, wh, bias_p);
  xz_gemm9<<<1024, 512, 0, stream>>>(x_bf, wx, bias_p, xz);

  // x_bf dead; init ring: slots 0..2 = poison (0xFF), slot 3 = zeros (h_{-1} = 0).
  hipMemsetAsync(ws, 0xFF, 196608, stream);
  hipMemsetAsync(ws + 196608, 0, 65536, stream);

  lstm14<<<32, 512, 0, stream>>>(wh, xz, hring, (float*)d_out);
}